// Round 11
// baseline (139.704 us; speedup 1.0000x reference)
//
#include <hip/hip_runtime.h>

#define B_ 32
#define M_ 4096
#define M1_ 4097
#define H_ 32
#define D_ 4096

typedef float float4_ __attribute__((ext_vector_type(4)));
typedef float f32x4 __attribute__((ext_vector_type(4)));
typedef short short8 __attribute__((ext_vector_type(8)));
typedef short short4_ __attribute__((ext_vector_type(4)));

#define KOFF 131072
#define VOFF 16912384

// ws layout (f32-word offsets)
#define Q_OFF     0u            // 34*32*128 = 139264
#define O_OFF     139264u       // 32*32*128 = 131072
#define YPART_OFF 270336u       // 8*131072  = 1048576
#define QPART_OFF 1318912u      // bf16: 16*139264 u16 = 1114112 words (dead after k_reduce_q)
#define APO_OFF   1318912u      // bf16: 512*32*128 u16 = 1048576 words (reuses qpart region)
#define MSUM_OFF  2433024u      // 512*32*2 = 32768 words -> total 2465792 f32 = 9.9 MB

#define WAITV(n) asm volatile("s_waitcnt vmcnt(" #n ")" ::: "memory")
#define SBAR() __builtin_amdgcn_sched_barrier(0)

__device__ __forceinline__ unsigned short f2bf(float f) {
  union { float f; unsigned u; } cv; cv.f = f;
  return (unsigned short)((cv.u + 0x7FFFu + ((cv.u >> 16) & 1u)) >> 16);
}
__device__ __forceinline__ float bf2f(unsigned short b) {
  union { unsigned u; float f; } cv; cv.u = ((unsigned)b) << 16;
  return cv.f;
}
__device__ __forceinline__ short8 pack8(const float* t) {
  short8 r;
#pragma unroll
  for (int j = 0; j < 8; ++j) r[j] = (short)f2bf(t[j]);
  return r;
}
__device__ __forceinline__ short8 load8cvt(const float* __restrict__ p) {
  float t[8];
  float4_ v0 = *(const float4_*)p;
  float4_ v1 = *(const float4_*)(p + 4);
#pragma unroll
  for (int j = 0; j < 4; ++j) { t[j] = v0[j]; t[4 + j] = v1[j]; }
  return pack8(t);
}
// nontemporal accessors for pure-streaming side buffers (qpart/apo/ypart/W/Po)
__device__ __forceinline__ float4_ ntld4(const float* p) {
  return __builtin_nontemporal_load((const float4_*)p);
}
__device__ __forceinline__ float ntldf(const float* p) {
  return __builtin_nontemporal_load(p);
}
__device__ __forceinline__ short8 load8cvt_nt(const float* __restrict__ p) {
  float t[8];
  float4_ v0 = ntld4(p);
  float4_ v1 = ntld4(p + 4);
#pragma unroll
  for (int j = 0; j < 4; ++j) { t[j] = v0[j]; t[4 + j] = v1[j]; }
  return pack8(t);
}
// async 16B global -> LDS (per-lane global src; wave-uniform LDS base + lane*16)
__device__ __forceinline__ void load_lds16(const float* g, float* l) {
  __builtin_amdgcn_global_load_lds(
      (const __attribute__((address_space(1))) unsigned int*)g,
      (__attribute__((address_space(3))) unsigned int*)l, 16, 0, 0);
}

// ---------------- kernel 1: projections, split-D=16 partials (256 d per chunk)
__global__ __launch_bounds__(256) void k_proj(const float* __restrict__ x,
    const float* __restrict__ Pq, const float* __restrict__ Pk,
    const float* __restrict__ Pv, unsigned short* __restrict__ qpart)
{
  int bid = blockIdx.x;
  int hh = bid >> 4;
  int c  = bid & 15;
  const float* W = (hh < 32) ? (Pq + (size_t)hh * D_ * 128)
                             : ((hh == 32) ? Pk : Pv);
  int d0 = c * 256;
  int tid = threadIdx.x;
  int w = tid >> 6, l = tid & 63, l15 = l & 15, lg = l >> 4;
  f32x4 acc[2][2] = {};          // [b-tile][n-tile]
  for (int ks = 0; ks < 8; ++ks) {
    int dk = d0 + ks * 32 + lg * 8;
    short8 af[2];
#pragma unroll
    for (int bt = 0; bt < 2; ++bt)
      af[bt] = load8cvt(x + (size_t)(bt * 16 + l15) * D_ + dk);
    short8 bf[2];
#pragma unroll
    for (int nti = 0; nti < 2; ++nti) {
      int col = (2 * w + nti) * 16 + l15;
      float t[8];
#pragma unroll
      for (int j = 0; j < 8; ++j) t[j] = ntldf(&W[(size_t)(dk + j) * 128 + col]);
      bf[nti] = pack8(t);
    }
#pragma unroll
    for (int bt = 0; bt < 2; ++bt)
#pragma unroll
      for (int nti = 0; nti < 2; ++nti)
        acc[bt][nti] = __builtin_amdgcn_mfma_f32_16x16x32_bf16(af[bt], bf[nti], acc[bt][nti], 0, 0, 0);
  }
#pragma unroll
  for (int bt = 0; bt < 2; ++bt)
#pragma unroll
    for (int nti = 0; nti < 2; ++nti) {
      int k = (2 * w + nti) * 16 + l15;
#pragma unroll
      for (int i = 0; i < 4; ++i) {
        int b = bt * 16 + lg * 4 + i;
        __builtin_nontemporal_store(f2bf(acc[bt][nti][i]),
            &qpart[(size_t)((c * 34 + hh) * 32 + b) * 128 + k]);
      }
    }
}

// ---------------- kernel 2: reduce bf16 projection partials; write new K/V cache row
__global__ __launch_bounds__(256) void k_reduce_q(const unsigned short* __restrict__ qpart,
    float* __restrict__ q, float* __restrict__ dout)
{
  int idx = blockIdx.x * 256 + threadIdx.x;   // 34*32*128 = 139264
  if (idx >= 34 * 32 * 128) return;
  float s = 0.f;
#pragma unroll
  for (int cc = 0; cc < 16; ++cc)
    s += bf2f(__builtin_nontemporal_load(&qpart[(size_t)cc * 139264 + idx]));
  q[idx] = s;
  int hh = idx >> 12;
  if (hh >= 32) {
    int b = (idx >> 7) & 31, k = idx & 127;
    size_t off = (hh == 32) ? (size_t)KOFF : (size_t)VOFF;
    __builtin_nontemporal_store(s, &dout[off + ((size_t)b * M1_ + M_) * 128 + k]);
  }
}

// ---------------- kernel 3: barrier-free wave-pipelined cache-copy + attention
// R8-best pipeline. NEW: K loaded twice from the same lines -- coalesced
// (8 x 1KB line-complete instrs -> K_new store, kills the +16-30 MB write
// amplification of frag-pattern stores) and frag-pattern (issued immediately
// after; MSHR/L2 merge -> no extra HBM fetch) for QK^T. Plain stores for
// K_new/V_new (nt worsened partial-line merging, R10).
#define ISSUE(T, KRC, KRF, VB) do { \
  const float* Kc_ = Kb + (T) * 2048; \
  /* coalesced 8 x (64 lanes x 16B contiguous) */ \
  _Pragma("unroll") \
  for (int i = 0; i < 8; ++i) KRC[i] = *(const float4_*)(Kc_ + (i * 64 + l) * 4); \
  /* frag pattern: same lines, merges in MSHR/L2 */ \
  const float* Krow_ = Kc_ + (size_t)l15 * 128; \
  _Pragma("unroll") \
  for (int ks = 0; ks < 4; ++ks) { \
    KRF[2 * ks]     = *(const float4_*)(Krow_ + ks * 32 + lg * 8); \
    KRF[2 * ks + 1] = *(const float4_*)(Krow_ + ks * 32 + lg * 8 + 4); \
  } \
  const float* Vc_ = Vb + (T) * 2048; \
  _Pragma("unroll") \
  for (int i = 0; i < 8; ++i) load_lds16(Vc_ + i * 256 + l * 4, VB + i * 256); \
} while (0)
// ISSUE = 24 vmem ops: [Kcoal 8][Kfrag 8][Vdma 8]

#define DO_CHUNK(T, KRC, KRF, VB) do { \
  /* K_new store: fully coalesced, line-complete per instruction */ \
  float* Knc_ = Knb + (T) * 2048; \
  _Pragma("unroll") \
  for (int i = 0; i < 8; ++i) *(float4_*)(Knc_ + (size_t)(i * 64 + l) * 4) = KRC[i]; \
  /* V_new store from LDS (coalesced) */ \
  float* Vnc_ = Vnb + (T) * 2048; \
  _Pragma("unroll") \
  for (int i = 0; i < 8; ++i) { \
    float4_ t_ = *(const float4_*)(VB + (i * 64 + l) * 4); \
    *(float4_*)(Vnc_ + (size_t)(i * 64 + l) * 4) = t_; \
  } \
  /* K frags in-register cvt */ \
  short8 kf_[4]; \
  _Pragma("unroll") \
  for (int ks = 0; ks < 4; ++ks) { \
    float tt_[8]; \
    _Pragma("unroll") \
    for (int j = 0; j < 4; ++j) { tt_[j] = KRF[2 * ks][j]; tt_[4 + j] = KRF[2 * ks + 1][j]; } \
    kf_[ks] = pack8(tt_); \
  } \
  /* QK^T: S[h][m], m = l15 */ \
  f32x4 sacc_[2] = {}; \
  _Pragma("unroll") \
  for (int ks = 0; ks < 4; ++ks) \
    _Pragma("unroll") \
    for (int ht = 0; ht < 2; ++ht) \
      sacc_[ht] = __builtin_amdgcn_mfma_f32_16x16x32_bf16(af[ht][ks], kf_[ks], sacc_[ht], 0, 0, 0); \
  /* online softmax (cross-lane within 16-lane groups) */ \
  _Pragma("unroll") \
  for (int ht = 0; ht < 2; ++ht) { \
    f32x4 mx_; \
    _Pragma("unroll") \
    for (int i = 0; i < 4; ++i) { \
      float v_ = sacc_[ht][i]; \
      v_ = fmaxf(v_, __shfl_xor(v_, 1)); v_ = fmaxf(v_, __shfl_xor(v_, 2)); \
      v_ = fmaxf(v_, __shfl_xor(v_, 4)); v_ = fmaxf(v_, __shfl_xor(v_, 8)); \
      mx_[i] = v_; \
    } \
    f32x4 fsc_; \
    _Pragma("unroll") \
    for (int i = 0; i < 4; ++i) { \
      float mn_ = fmaxf(mrun[ht][i], mx_[i]); \
      fsc_[i] = __expf(mrun[ht][i] - mn_); \
      mrun[ht][i] = mn_; \
    } \
    _Pragma("unroll") \
    for (int vt = 0; vt < 8; ++vt) oacc[ht][vt] *= fsc_; \
    _Pragma("unroll") \
    for (int i = 0; i < 4; ++i) { \
      float p_ = __expf(sacc_[ht][i] - mrun[ht][i]); \
      lsum[ht][i] = lsum[ht][i] * fsc_[i] + p_; \
      Plds[w][ht * 16 + lg * 4 + i][l15] = f2bf(p_); \
    } \
  } \
  asm volatile("" ::: "memory"); \
  /* PV: 16x16x32 with upper K-half zeroed (contraction m=16) */ \
  short8 z_ = {}; \
  short8 pa_[2]; \
  _Pragma("unroll") \
  for (int ht = 0; ht < 2; ++ht) \
    pa_[ht] = (lg < 2) ? *(const short8*)&Plds[w][ht * 16 + l15][lg * 8] : z_; \
  _Pragma("unroll") \
  for (int vt = 0; vt < 8; ++vt) { \
    short8 bfv_ = z_; \
    if (lg < 2) { \
      float t_[8]; \
      _Pragma("unroll") \
      for (int j = 0; j < 8; ++j) t_[j] = VB[(lg * 8 + j) * 128 + vt * 16 + l15]; \
      bfv_ = pack8(t_); \
    } \
    _Pragma("unroll") \
    for (int ht = 0; ht < 2; ++ht) \
      oacc[ht][vt] = __builtin_amdgcn_mfma_f32_16x16x32_bf16(pa_[ht], bfv_, oacc[ht][vt], 0, 0, 0); \
  } \
} while (0)
// DO_CHUNK = 16 vmem stores: [stK 8][stV 8]

__global__ __launch_bounds__(256, 2) void k_attn(const float* __restrict__ Kp,
    const float* __restrict__ Vp, const float* __restrict__ q,
    float* __restrict__ dout, unsigned short* __restrict__ apo,
    float* __restrict__ msum)
{
  __shared__ float Vbuf[4][2][2048];          // per-wave V dbuf (DMA dst), 64 KB
  __shared__ unsigned short Plds[4][32][16];  // per-wave P tile, 4 KB
  __shared__ float Mh[4][32], Sh[4][32];      // per-wave softmax stats (epilogue)
  int bid = blockIdx.x;
  int b = bid >> 4;
  int tid = threadIdx.x, w = tid >> 6, l = tid & 63, l15 = l & 15, lg = l >> 4;
  int wid = (bid & 15) * 4 + w;               // 0..63 per b
  const float* Kb = Kp + ((size_t)b * M_ + wid * 64) * 128;
  const float* Vb = Vp + ((size_t)b * M_ + wid * 64) * 128;
  float* Knb = dout + KOFF + ((size_t)b * M1_ + wid * 64) * 128;
  float* Vnb = dout + VOFF + ((size_t)b * M1_ + wid * 64) * 128;
  float* vb0 = &Vbuf[w][0][0];
  float* vb1 = &Vbuf[w][1][0];

  // q fragments, once per wave (16 b128 loads; q is hot/cached)
  short8 af[2][4];
#pragma unroll
  for (int ks = 0; ks < 4; ++ks)
#pragma unroll
    for (int ht = 0; ht < 2; ++ht)
      af[ht][ks] = load8cvt(q + (size_t)((ht * 16 + l15) * 32 + b) * 128 + ks * 32 + lg * 8);

  float4_ krA[8], krB[8], kfrA[8], kfrB[8];
  f32x4 mrun[2], lsum[2], oacc[2][8];
#pragma unroll
  for (int ht = 0; ht < 2; ++ht) {
#pragma unroll
    for (int i = 0; i < 4; ++i) { mrun[ht][i] = -3e38f; lsum[ht][i] = 0.f; }
#pragma unroll
    for (int vt = 0; vt < 8; ++vt) oacc[ht][vt] = f32x4{0.f, 0.f, 0.f, 0.f};
  }

  // vmcnt budget (HW cap 63). q=16, ISSUE=24, DO_CHUNK stores=16.
  ISSUE(0, krA, kfrA, vb0); SBAR();   // 40
  WAITV(24); SBAR();                  // drain q; I0 in flight (24)
  ISSUE(1, krB, kfrB, vb1); SBAR();   // 48
  WAITV(24); SBAR();                  // drain I0 (K0c,K0f,V0 done); leaves I1
  DO_CHUNK(0, krA, kfrA, vb0);        // +16 -> 40
  WAITV(16); SBAR();                  // drain I1 (chunk1 ready); leaves st0 (16)
  ISSUE(2, krA, kfrA, vb0); SBAR();   // 40
  DO_CHUNK(1, krB, kfrB, vb1);        // +16 -> 56 (peak)
  WAITV(16); SBAR();                  // drain st0+I2 (chunk2 ready); leaves st1
  ISSUE(3, krB, kfrB, vb1); SBAR();   // 40
  DO_CHUNK(2, krA, kfrA, vb0);        // +16 -> 56
  WAITV(16); SBAR();                  // drain st1+I3 (chunk3 ready); leaves st2
  DO_CHUNK(3, krB, kfrB, vb1);        // -> 32

  // ---- epilogue: per-wave sum reduce, then 4-wave flash-merge in LDS ----
#pragma unroll
  for (int ht = 0; ht < 2; ++ht)
#pragma unroll
    for (int i = 0; i < 4; ++i) {
      float s = lsum[ht][i];
      s += __shfl_xor(s, 1); s += __shfl_xor(s, 2);
      s += __shfl_xor(s, 4); s += __shfl_xor(s, 8);
      lsum[ht][i] = s;
    }
  if (l15 == 0) {
#pragma unroll
    for (int ht = 0; ht < 2; ++ht)
#pragma unroll
      for (int i = 0; i < 4; ++i) {
        int h = ht * 16 + lg * 4 + i;
        Mh[w][h] = mrun[ht][i];
        Sh[w][h] = lsum[ht][i];
      }
  }
  __syncthreads();
  // scale own O by exp(m_w - m*) into this wave's (now dead) Vbuf region
  float* Ob = &Vbuf[w][0][0];
#pragma unroll
  for (int ht = 0; ht < 2; ++ht)
#pragma unroll
    for (int i = 0; i < 4; ++i) {
      int h = ht * 16 + lg * 4 + i;
      float ms = fmaxf(fmaxf(Mh[0][h], Mh[1][h]), fmaxf(Mh[2][h], Mh[3][h]));
      float f = __expf(mrun[ht][i] - ms);
#pragma unroll
      for (int vt = 0; vt < 8; ++vt)
        Ob[h * 128 + vt * 16 + l15] = oacc[ht][vt][i] * f;
    }
  __syncthreads();
  int blk = bid & 15;
  size_t sblk = ((size_t)b * 16 + blk) * 32;
  if (tid < 32) {
    int h = tid;
    float ms = fmaxf(fmaxf(Mh[0][h], Mh[1][h]), fmaxf(Mh[2][h], Mh[3][h]));
    float ss = Sh[0][h] * __expf(Mh[0][h] - ms) + Sh[1][h] * __expf(Mh[1][h] - ms)
             + Sh[2][h] * __expf(Mh[2][h] - ms) + Sh[3][h] * __expf(Mh[3][h] - ms);
    msum[(sblk + h) * 2]     = ms;
    msum[(sblk + h) * 2 + 1] = ss;
  }
  const float* Vall = &Vbuf[0][0][0];
  for (int idx = tid; idx < 4096; idx += 256) {
    float s = Vall[idx] + Vall[4096 + idx] + Vall[8192 + idx] + Vall[12288 + idx];
    __builtin_nontemporal_store(f2bf(s), &apo[(sblk + (idx >> 7)) * 128 + (idx & 127)]);
  }
}

// ---------------- kernel 4: combine 16 block partials + exact extra-token -> o
__global__ __launch_bounds__(256) void k_combine(const unsigned short* __restrict__ apo,
    const float* __restrict__ msum, const float* __restrict__ q, float* __restrict__ o)
{
  __shared__ float redN[4][128];
  __shared__ float redD[4];
  int bid = blockIdx.x;            // 1024: b*32+h
  int b = bid >> 5, h = bid & 31;
  int tid = threadIdx.x, w = tid >> 6, l = tid & 63;

  // exact f32 extra-token logit: e = q[h] . k_new
  const float* qh = q + (size_t)(h * 32 + b) * 128;
  const float* kn = q + (size_t)(1024 + b) * 128;
  const float* vn = q + (size_t)(1056 + b) * 128;
  float e = qh[2 * l] * kn[2 * l] + qh[2 * l + 1] * kn[2 * l + 1];
#pragma unroll
  for (int d = 1; d < 64; d <<= 1) e += __shfl_xor(e, d);

  float gm = (l < 16) ? msum[((size_t)(b * 16 + l) * 32 + h) * 2] : -3e38f;
#pragma unroll
  for (int d = 1; d < 64; d <<= 1) gm = fmaxf(gm, __shfl_xor(gm, d));
  gm = fmaxf(gm, e);
  float pe = __expf(e - gm);

  float num0 = 0.f, num1 = 0.f, den = 0.f;
#pragma unroll
  for (int i = 0; i < 4; ++i) {
    int cc = w * 4 + i;
    size_t slot = (size_t)(b * 16 + cc) * 32 + h;
    float sc = __expf(msum[slot * 2] - gm);
    den += sc * msum[slot * 2 + 1];
    unsigned pp = __builtin_nontemporal_load((const unsigned*)&apo[slot * 128 + l * 2]);
    num0 += sc * bf2f((unsigned short)(pp & 0xFFFFu));
    num1 += sc * bf2f((unsigned short)(pp >> 16));
  }
  redN[w][l * 2] = num0;
  redN[w][l * 2 + 1] = num1;
  if (l == 0) redD[w] = den + (w == 0 ? pe : 0.f);
  __syncthreads();
  if (tid < 128) {
    float num = redN[0][tid] + redN[1][tid] + redN[2][tid] + redN[3][tid] + pe * vn[tid];
    float dd  = redD[0] + redD[1] + redD[2] + redD[3];
    o[((size_t)(b * 32 + h)) * 128 + tid] = num / dd;
  }
}

// ---------------- kernel 5: y partials = o x P_o  (grid 512 = 64 d-tiles x 8 head-groups)
__global__ __launch_bounds__(256) void k_out(const float* __restrict__ o,
    const float* __restrict__ Po, float* __restrict__ ypart)
{
  int bid = blockIdx.x;
  int dt = bid >> 3, hg = bid & 7;
  int tid = threadIdx.x, w = tid >> 6, l = tid & 63, l15 = l & 15, lg = l >> 4;
  int d = dt * 64 + w * 16 + l15;
  f32x4 acc[2] = {};               // [b-tile]
  for (int hi = 0; hi < 4; ++hi) {
    int h = hg * 4 + hi;
#pragma unroll
    for (int ks = 0; ks < 4; ++ks) {
      short8 af[2];
#pragma unroll
      for (int bt = 0; bt < 2; ++bt)
        af[bt] = load8cvt(o + ((size_t)((bt * 16 + l15) * 32 + h)) * 128 + ks * 32 + lg * 8);
      short8 bf = load8cvt_nt(Po + ((size_t)h * D_ + d) * 128 + ks * 32 + lg * 8);
#pragma unroll
      for (int bt = 0; bt < 2; ++bt)
        acc[bt] = __builtin_amdgcn_mfma_f32_16x16x32_bf16(af[bt], bf, acc[bt], 0, 0, 0);
    }
  }
#pragma unroll
  for (int bt = 0; bt < 2; ++bt)
#pragma unroll
    for (int i = 0; i < 4; ++i) {
      int b = bt * 16 + lg * 4 + i;
      __builtin_nontemporal_store(acc[bt][i],
          &ypart[((size_t)(hg * 32 + b)) * 4096 + d]);
    }
}

// ---------------- kernel 6: reduce y partials -> y
__global__ __launch_bounds__(256) void k_reduce_y(const float* __restrict__ ypart,
    float* __restrict__ dout)
{
  int idx = blockIdx.x * 256 + threadIdx.x;  // 131072
  float s = 0.f;
#pragma unroll
  for (int g = 0; g < 8; ++g)
    s += __builtin_nontemporal_load(&ypart[(size_t)g * 131072 + idx]);
  dout[idx] = s;
}

extern "C" void kernel_launch(void* const* d_in, const int* in_sizes, int n_in,
                              void* d_out, int out_size, void* d_ws, size_t ws_size,
                              hipStream_t stream) {
  (void)in_sizes; (void)n_in; (void)out_size; (void)ws_size;
  const float* x  = (const float*)d_in[0];
  const float* Kp = (const float*)d_in[1];
  const float* Vp = (const float*)d_in[2];
  const float* Pq = (const float*)d_in[3];
  const float* Pk = (const float*)d_in[4];
  const float* Pv = (const float*)d_in[5];
  const float* Po = (const float*)d_in[6];
  float* out = (float*)d_out;
  float* ws  = (float*)d_ws;
  float* q     = ws + Q_OFF;
  float* o     = ws + O_OFF;
  float* ypart = ws + YPART_OFF;
  unsigned short* qpart = (unsigned short*)(ws + QPART_OFF);
  unsigned short* apo   = (unsigned short*)(ws + APO_OFF);
  float* msum  = ws + MSUM_OFF;

  hipLaunchKernelGGL(k_proj,     dim3(544),  dim3(256), 0, stream, x, Pq, Pk, Pv, qpart);
  hipLaunchKernelGGL(k_reduce_q, dim3(544),  dim3(256), 0, stream, qpart, q, out);
  hipLaunchKernelGGL(k_attn,     dim3(512),  dim3(256), 0, stream, Kp, Vp, q, out, apo, msum);
  hipLaunchKernelGGL(k_combine,  dim3(1024), dim3(256), 0, stream, apo, msum, q, o);
  hipLaunchKernelGGL(k_out,      dim3(512),  dim3(256), 0, stream, o, Po, ypart);
  hipLaunchKernelGGL(k_reduce_y, dim3(512),  dim3(256), 0, stream, ypart, out);
}

// Round 12
// 135.778 us; speedup vs baseline: 1.0289x; 1.0289x over previous
//
#include <hip/hip_runtime.h>

#define B_ 32
#define M_ 4096
#define M1_ 4097
#define H_ 32
#define D_ 4096

typedef float float4_ __attribute__((ext_vector_type(4)));
typedef float f32x4 __attribute__((ext_vector_type(4)));
typedef short short8 __attribute__((ext_vector_type(8)));
typedef short short4_ __attribute__((ext_vector_type(4)));

#define KOFF 131072
#define VOFF 16912384

// ws layout (f32-word offsets)
#define Q_OFF     0u            // 34*32*128 = 139264
#define O_OFF     139264u       // 32*32*128 = 131072
#define YPART_OFF 270336u       // 8*131072  = 1048576
#define QPART_OFF 1318912u      // bf16: 16*139264 u16 = 1114112 words (dead after k_reduce_q)
#define APO_OFF   1318912u      // bf16: 512*32*128 u16 = 1048576 words (reuses qpart region)
#define MSUM_OFF  2433024u      // 512*32*2 = 32768 words -> total 2465792 f32 = 9.9 MB

#define WAITV(n) asm volatile("s_waitcnt vmcnt(" #n ")" ::: "memory")
#define SBAR() __builtin_amdgcn_sched_barrier(0)

__device__ __forceinline__ unsigned short f2bf(float f) {
  union { float f; unsigned u; } cv; cv.f = f;
  return (unsigned short)((cv.u + 0x7FFFu + ((cv.u >> 16) & 1u)) >> 16);
}
__device__ __forceinline__ float bf2f(unsigned short b) {
  union { unsigned u; float f; } cv; cv.u = ((unsigned)b) << 16;
  return cv.f;
}
__device__ __forceinline__ short8 pack8(const float* t) {
  short8 r;
#pragma unroll
  for (int j = 0; j < 8; ++j) r[j] = (short)f2bf(t[j]);
  return r;
}
__device__ __forceinline__ short8 load8cvt(const float* __restrict__ p) {
  float t[8];
  float4_ v0 = *(const float4_*)p;
  float4_ v1 = *(const float4_*)(p + 4);
#pragma unroll
  for (int j = 0; j < 4; ++j) { t[j] = v0[j]; t[4 + j] = v1[j]; }
  return pack8(t);
}
// nontemporal accessors for pure-streaming side buffers (qpart/apo/ypart/W/Po)
__device__ __forceinline__ float4_ ntld4(const float* p) {
  return __builtin_nontemporal_load((const float4_*)p);
}
__device__ __forceinline__ float ntldf(const float* p) {
  return __builtin_nontemporal_load(p);
}
__device__ __forceinline__ short8 load8cvt_nt(const float* __restrict__ p) {
  float t[8];
  float4_ v0 = ntld4(p);
  float4_ v1 = ntld4(p + 4);
#pragma unroll
  for (int j = 0; j < 4; ++j) { t[j] = v0[j]; t[4 + j] = v1[j]; }
  return pack8(t);
}
// async 16B global -> LDS (per-lane global src; wave-uniform LDS base + lane*16)
__device__ __forceinline__ void load_lds16(const float* g, float* l) {
  __builtin_amdgcn_global_load_lds(
      (const __attribute__((address_space(1))) unsigned int*)g,
      (__attribute__((address_space(3))) unsigned int*)l, 16, 0, 0);
}

// ---------------- kernel 1: projections, split-D=16 partials (256 d per chunk)
__global__ __launch_bounds__(256) void k_proj(const float* __restrict__ x,
    const float* __restrict__ Pq, const float* __restrict__ Pk,
    const float* __restrict__ Pv, unsigned short* __restrict__ qpart)
{
  int bid = blockIdx.x;
  int hh = bid >> 4;
  int c  = bid & 15;
  const float* W = (hh < 32) ? (Pq + (size_t)hh * D_ * 128)
                             : ((hh == 32) ? Pk : Pv);
  int d0 = c * 256;
  int tid = threadIdx.x;
  int w = tid >> 6, l = tid & 63, l15 = l & 15, lg = l >> 4;
  f32x4 acc[2][2] = {};          // [b-tile][n-tile]
  for (int ks = 0; ks < 8; ++ks) {
    int dk = d0 + ks * 32 + lg * 8;
    short8 af[2];
#pragma unroll
    for (int bt = 0; bt < 2; ++bt)
      af[bt] = load8cvt(x + (size_t)(bt * 16 + l15) * D_ + dk);
    short8 bf[2];
#pragma unroll
    for (int nti = 0; nti < 2; ++nti) {
      int col = (2 * w + nti) * 16 + l15;
      float t[8];
#pragma unroll
      for (int j = 0; j < 8; ++j) t[j] = ntldf(&W[(size_t)(dk + j) * 128 + col]);
      bf[nti] = pack8(t);
    }
#pragma unroll
    for (int bt = 0; bt < 2; ++bt)
#pragma unroll
      for (int nti = 0; nti < 2; ++nti)
        acc[bt][nti] = __builtin_amdgcn_mfma_f32_16x16x32_bf16(af[bt], bf[nti], acc[bt][nti], 0, 0, 0);
  }
#pragma unroll
  for (int bt = 0; bt < 2; ++bt)
#pragma unroll
    for (int nti = 0; nti < 2; ++nti) {
      int k = (2 * w + nti) * 16 + l15;
#pragma unroll
      for (int i = 0; i < 4; ++i) {
        int b = bt * 16 + lg * 4 + i;
        __builtin_nontemporal_store(f2bf(acc[bt][nti][i]),
            &qpart[(size_t)((c * 34 + hh) * 32 + b) * 128 + k]);
      }
    }
}

// ---------------- kernel 2: reduce bf16 projection partials; write new K/V cache row
__global__ __launch_bounds__(256) void k_reduce_q(const unsigned short* __restrict__ qpart,
    float* __restrict__ q, float* __restrict__ dout)
{
  int idx = blockIdx.x * 256 + threadIdx.x;   // 34*32*128 = 139264
  if (idx >= 34 * 32 * 128) return;
  float s = 0.f;
#pragma unroll
  for (int cc = 0; cc < 16; ++cc)
    s += bf2f(__builtin_nontemporal_load(&qpart[(size_t)cc * 139264 + idx]));
  q[idx] = s;
  int hh = idx >> 12;
  if (hh >= 32) {
    int b = (idx >> 7) & 31, k = idx & 127;
    size_t off = (hh == 32) ? (size_t)KOFF : (size_t)VOFF;
    __builtin_nontemporal_store(s, &dout[off + ((size_t)b * M1_ + M_) * 128 + k]);
  }
}

// ---------------- kernel 2.5: PURE streaming cache copy (m13 float4-copy pattern)
// 4096 blocks x 256 threads, 8 float4/thread, contiguous per block.
// nt stores: don't let the write stream evict K/V reads from L3 (k_attn2
// re-reads them right after).
__global__ __launch_bounds__(256) void k_copy(const float* __restrict__ Kp,
    const float* __restrict__ Vp, float* __restrict__ dout)
{
  int bid = blockIdx.x;
  int arr = bid >> 11;             // 0: K, 1: V
  int blk = bid & 2047;
  const float4_* src = (const float4_*)(arr ? Vp : Kp);
  float* dstbase = dout + (arr ? VOFF : KOFF);
  size_t f0 = (size_t)blk * 2048;  // 2048 float4 = 32 KB per block, within one batch
  size_t b = f0 >> 17;             // f0 / 131072 (131072 float4 per batch)
  size_t r0 = f0 & 131071;
  float* dst = dstbase + b * ((size_t)M1_ * 128);
  float4_ t[8];
#pragma unroll
  for (int i = 0; i < 8; ++i) t[i] = src[f0 + i * 256 + threadIdx.x];
#pragma unroll
  for (int i = 0; i < 8; ++i)
    __builtin_nontemporal_store(t[i], (float4_*)(dst + (r0 + i * 256 + threadIdx.x) * 4));
}

// ---------------- kernel 3: attention-only (no cache stores), wave-pipelined
// R10 pipeline minus K_new/V_new stores; K/V reads should be L3-hot from k_copy.
#define ISSUE(T, KR, VB) do { \
  const float* Krow_ = Kb + (T) * 2048 + (size_t)l15 * 128; \
  _Pragma("unroll") \
  for (int ks = 0; ks < 4; ++ks) { \
    KR[2 * ks]     = *(const float4_*)(Krow_ + ks * 32 + lg * 8); \
    KR[2 * ks + 1] = *(const float4_*)(Krow_ + ks * 32 + lg * 8 + 4); \
  } \
  const float* Vc_ = Vb + (T) * 2048; \
  _Pragma("unroll") \
  for (int i = 0; i < 8; ++i) load_lds16(Vc_ + i * 256 + l * 4, VB + i * 256); \
} while (0)
// ISSUE = 16 vmem ops: [Kfrag 8][Vdma 8]

#define DO_CHUNK(T, KR, VB) do { \
  /* K frags in-register cvt */ \
  short8 kf_[4]; \
  _Pragma("unroll") \
  for (int ks = 0; ks < 4; ++ks) { \
    float tt_[8]; \
    _Pragma("unroll") \
    for (int j = 0; j < 4; ++j) { tt_[j] = KR[2 * ks][j]; tt_[4 + j] = KR[2 * ks + 1][j]; } \
    kf_[ks] = pack8(tt_); \
  } \
  /* QK^T: S[h][m], m = l15 */ \
  f32x4 sacc_[2] = {}; \
  _Pragma("unroll") \
  for (int ks = 0; ks < 4; ++ks) \
    _Pragma("unroll") \
    for (int ht = 0; ht < 2; ++ht) \
      sacc_[ht] = __builtin_amdgcn_mfma_f32_16x16x32_bf16(af[ht][ks], kf_[ks], sacc_[ht], 0, 0, 0); \
  /* online softmax (cross-lane within 16-lane groups) */ \
  _Pragma("unroll") \
  for (int ht = 0; ht < 2; ++ht) { \
    f32x4 mx_; \
    _Pragma("unroll") \
    for (int i = 0; i < 4; ++i) { \
      float v_ = sacc_[ht][i]; \
      v_ = fmaxf(v_, __shfl_xor(v_, 1)); v_ = fmaxf(v_, __shfl_xor(v_, 2)); \
      v_ = fmaxf(v_, __shfl_xor(v_, 4)); v_ = fmaxf(v_, __shfl_xor(v_, 8)); \
      mx_[i] = v_; \
    } \
    f32x4 fsc_; \
    _Pragma("unroll") \
    for (int i = 0; i < 4; ++i) { \
      float mn_ = fmaxf(mrun[ht][i], mx_[i]); \
      fsc_[i] = __expf(mrun[ht][i] - mn_); \
      mrun[ht][i] = mn_; \
    } \
    _Pragma("unroll") \
    for (int vt = 0; vt < 8; ++vt) oacc[ht][vt] *= fsc_; \
    _Pragma("unroll") \
    for (int i = 0; i < 4; ++i) { \
      float p_ = __expf(sacc_[ht][i] - mrun[ht][i]); \
      lsum[ht][i] = lsum[ht][i] * fsc_[i] + p_; \
      Plds[w][ht * 16 + lg * 4 + i][l15] = f2bf(p_); \
    } \
  } \
  asm volatile("" ::: "memory"); \
  /* PV: 16x16x32 with upper K-half zeroed (contraction m=16) */ \
  short8 z_ = {}; \
  short8 pa_[2]; \
  _Pragma("unroll") \
  for (int ht = 0; ht < 2; ++ht) \
    pa_[ht] = (lg < 2) ? *(const short8*)&Plds[w][ht * 16 + l15][lg * 8] : z_; \
  _Pragma("unroll") \
  for (int vt = 0; vt < 8; ++vt) { \
    short8 bfv_ = z_; \
    if (lg < 2) { \
      float t_[8]; \
      _Pragma("unroll") \
      for (int j = 0; j < 8; ++j) t_[j] = VB[(lg * 8 + j) * 128 + vt * 16 + l15]; \
      bfv_ = pack8(t_); \
    } \
    _Pragma("unroll") \
    for (int ht = 0; ht < 2; ++ht) \
      oacc[ht][vt] = __builtin_amdgcn_mfma_f32_16x16x32_bf16(pa_[ht], bfv_, oacc[ht][vt], 0, 0, 0); \
  } \
} while (0)

__global__ __launch_bounds__(256, 2) void k_attn(const float* __restrict__ Kp,
    const float* __restrict__ Vp, const float* __restrict__ q,
    unsigned short* __restrict__ apo, float* __restrict__ msum)
{
  __shared__ float Vbuf[4][2][2048];          // per-wave V dbuf (DMA dst), 64 KB
  __shared__ unsigned short Plds[4][32][16];  // per-wave P tile, 4 KB
  __shared__ float Mh[4][32], Sh[4][32];      // per-wave softmax stats (epilogue)
  int bid = blockIdx.x;
  int b = bid >> 4;
  int tid = threadIdx.x, w = tid >> 6, l = tid & 63, l15 = l & 15, lg = l >> 4;
  int wid = (bid & 15) * 4 + w;               // 0..63 per b
  const float* Kb = Kp + ((size_t)b * M_ + wid * 64) * 128;
  const float* Vb = Vp + ((size_t)b * M_ + wid * 64) * 128;
  float* vb0 = &Vbuf[w][0][0];
  float* vb1 = &Vbuf[w][1][0];

  // q fragments, once per wave (16 b128 loads; q is hot/cached)
  short8 af[2][4];
#pragma unroll
  for (int ks = 0; ks < 4; ++ks)
#pragma unroll
    for (int ht = 0; ht < 2; ++ht)
      af[ht][ks] = load8cvt(q + (size_t)((ht * 16 + l15) * 32 + b) * 128 + ks * 32 + lg * 8);

  float4_ krA[8], krB[8];
  f32x4 mrun[2], lsum[2], oacc[2][8];
#pragma unroll
  for (int ht = 0; ht < 2; ++ht) {
#pragma unroll
    for (int i = 0; i < 4; ++i) { mrun[ht][i] = -3e38f; lsum[ht][i] = 0.f; }
#pragma unroll
    for (int vt = 0; vt < 8; ++vt) oacc[ht][vt] = f32x4{0.f, 0.f, 0.f, 0.f};
  }

  // vmcnt: q=16, ISSUE=16 each (loads only, no stores in the main loop)
  ISSUE(0, krA, vb0); SBAR();   // q16 + I0 = 32
  ISSUE(1, krB, vb1); SBAR();   // 48
  WAITV(16); SBAR();            // drain q + I0; I1 in flight
  DO_CHUNK(0, krA, vb0);
  ISSUE(2, krA, vb0); SBAR();   // I1 + I2 = 32
  WAITV(16); SBAR();            // drain I1; I2 in flight
  DO_CHUNK(1, krB, vb1);
  ISSUE(3, krB, vb1); SBAR();   // I2 + I3 = 32
  WAITV(16); SBAR();            // drain I2; I3 in flight
  DO_CHUNK(2, krA, vb0);
  WAITV(0); SBAR();             // drain I3
  DO_CHUNK(3, krB, vb1);

  // ---- epilogue: per-wave sum reduce, then 4-wave flash-merge in LDS ----
#pragma unroll
  for (int ht = 0; ht < 2; ++ht)
#pragma unroll
    for (int i = 0; i < 4; ++i) {
      float s = lsum[ht][i];
      s += __shfl_xor(s, 1); s += __shfl_xor(s, 2);
      s += __shfl_xor(s, 4); s += __shfl_xor(s, 8);
      lsum[ht][i] = s;
    }
  if (l15 == 0) {
#pragma unroll
    for (int ht = 0; ht < 2; ++ht)
#pragma unroll
      for (int i = 0; i < 4; ++i) {
        int h = ht * 16 + lg * 4 + i;
        Mh[w][h] = mrun[ht][i];
        Sh[w][h] = lsum[ht][i];
      }
  }
  __syncthreads();
  // scale own O by exp(m_w - m*) into this wave's (now dead) Vbuf region
  float* Ob = &Vbuf[w][0][0];
#pragma unroll
  for (int ht = 0; ht < 2; ++ht)
#pragma unroll
    for (int i = 0; i < 4; ++i) {
      int h = ht * 16 + lg * 4 + i;
      float ms = fmaxf(fmaxf(Mh[0][h], Mh[1][h]), fmaxf(Mh[2][h], Mh[3][h]));
      float f = __expf(mrun[ht][i] - ms);
#pragma unroll
      for (int vt = 0; vt < 8; ++vt)
        Ob[h * 128 + vt * 16 + l15] = oacc[ht][vt][i] * f;
    }
  __syncthreads();
  int blk = bid & 15;
  size_t sblk = ((size_t)b * 16 + blk) * 32;
  if (tid < 32) {
    int h = tid;
    float ms = fmaxf(fmaxf(Mh[0][h], Mh[1][h]), fmaxf(Mh[2][h], Mh[3][h]));
    float ss = Sh[0][h] * __expf(Mh[0][h] - ms) + Sh[1][h] * __expf(Mh[1][h] - ms)
             + Sh[2][h] * __expf(Mh[2][h] - ms) + Sh[3][h] * __expf(Mh[3][h] - ms);
    msum[(sblk + h) * 2]     = ms;
    msum[(sblk + h) * 2 + 1] = ss;
  }
  const float* Vall = &Vbuf[0][0][0];
  for (int idx = tid; idx < 4096; idx += 256) {
    float s = Vall[idx] + Vall[4096 + idx] + Vall[8192 + idx] + Vall[12288 + idx];
    __builtin_nontemporal_store(f2bf(s), &apo[(sblk + (idx >> 7)) * 128 + (idx & 127)]);
  }
}

// ---------------- kernel 4: combine 16 block partials + exact extra-token -> o
__global__ __launch_bounds__(256) void k_combine(const unsigned short* __restrict__ apo,
    const float* __restrict__ msum, const float* __restrict__ q, float* __restrict__ o)
{
  __shared__ float redN[4][128];
  __shared__ float redD[4];
  int bid = blockIdx.x;            // 1024: b*32+h
  int b = bid >> 5, h = bid & 31;
  int tid = threadIdx.x, w = tid >> 6, l = tid & 63;

  // exact f32 extra-token logit: e = q[h] . k_new
  const float* qh = q + (size_t)(h * 32 + b) * 128;
  const float* kn = q + (size_t)(1024 + b) * 128;
  const float* vn = q + (size_t)(1056 + b) * 128;
  float e = qh[2 * l] * kn[2 * l] + qh[2 * l + 1] * kn[2 * l + 1];
#pragma unroll
  for (int d = 1; d < 64; d <<= 1) e += __shfl_xor(e, d);

  float gm = (l < 16) ? msum[((size_t)(b * 16 + l) * 32 + h) * 2] : -3e38f;
#pragma unroll
  for (int d = 1; d < 64; d <<= 1) gm = fmaxf(gm, __shfl_xor(gm, d));
  gm = fmaxf(gm, e);
  float pe = __expf(e - gm);

  float num0 = 0.f, num1 = 0.f, den = 0.f;
#pragma unroll
  for (int i = 0; i < 4; ++i) {
    int cc = w * 4 + i;
    size_t slot = (size_t)(b * 16 + cc) * 32 + h;
    float sc = __expf(msum[slot * 2] - gm);
    den += sc * msum[slot * 2 + 1];
    unsigned pp = __builtin_nontemporal_load((const unsigned*)&apo[slot * 128 + l * 2]);
    num0 += sc * bf2f((unsigned short)(pp & 0xFFFFu));
    num1 += sc * bf2f((unsigned short)(pp >> 16));
  }
  redN[w][l * 2] = num0;
  redN[w][l * 2 + 1] = num1;
  if (l == 0) redD[w] = den + (w == 0 ? pe : 0.f);
  __syncthreads();
  if (tid < 128) {
    float num = redN[0][tid] + redN[1][tid] + redN[2][tid] + redN[3][tid] + pe * vn[tid];
    float dd  = redD[0] + redD[1] + redD[2] + redD[3];
    o[((size_t)(b * 32 + h)) * 128 + tid] = num / dd;
  }
}

// ---------------- kernel 5: y partials = o x P_o  (grid 512 = 64 d-tiles x 8 head-groups)
__global__ __launch_bounds__(256) void k_out(const float* __restrict__ o,
    const float* __restrict__ Po, float* __restrict__ ypart)
{
  int bid = blockIdx.x;
  int dt = bid >> 3, hg = bid & 7;
  int tid = threadIdx.x, w = tid >> 6, l = tid & 63, l15 = l & 15, lg = l >> 4;
  int d = dt * 64 + w * 16 + l15;
  f32x4 acc[2] = {};               // [b-tile]
  for (int hi = 0; hi < 4; ++hi) {
    int h = hg * 4 + hi;
#pragma unroll
    for (int ks = 0; ks < 4; ++ks) {
      short8 af[2];
#pragma unroll
      for (int bt = 0; bt < 2; ++bt)
        af[bt] = load8cvt(o + ((size_t)((bt * 16 + l15) * 32 + h)) * 128 + ks * 32 + lg * 8);
      short8 bf = load8cvt_nt(Po + ((size_t)h * D_ + d) * 128 + ks * 32 + lg * 8);
#pragma unroll
      for (int bt = 0; bt < 2; ++bt)
        acc[bt] = __builtin_amdgcn_mfma_f32_16x16x32_bf16(af[bt], bf, acc[bt], 0, 0, 0);
    }
  }
#pragma unroll
  for (int bt = 0; bt < 2; ++bt)
#pragma unroll
    for (int i = 0; i < 4; ++i) {
      int b = bt * 16 + lg * 4 + i;
      __builtin_nontemporal_store(acc[bt][i],
          &ypart[((size_t)(hg * 32 + b)) * 4096 + d]);
    }
}

// ---------------- kernel 6: reduce y partials -> y
__global__ __launch_bounds__(256) void k_reduce_y(const float* __restrict__ ypart,
    float* __restrict__ dout)
{
  int idx = blockIdx.x * 256 + threadIdx.x;  // 131072
  float s = 0.f;
#pragma unroll
  for (int g = 0; g < 8; ++g)
    s += __builtin_nontemporal_load(&ypart[(size_t)g * 131072 + idx]);
  dout[idx] = s;
}

extern "C" void kernel_launch(void* const* d_in, const int* in_sizes, int n_in,
                              void* d_out, int out_size, void* d_ws, size_t ws_size,
                              hipStream_t stream) {
  (void)in_sizes; (void)n_in; (void)out_size; (void)ws_size;
  const float* x  = (const float*)d_in[0];
  const float* Kp = (const float*)d_in[1];
  const float* Vp = (const float*)d_in[2];
  const float* Pq = (const float*)d_in[3];
  const float* Pk = (const float*)d_in[4];
  const float* Pv = (const float*)d_in[5];
  const float* Po = (const float*)d_in[6];
  float* out = (float*)d_out;
  float* ws  = (float*)d_ws;
  float* q     = ws + Q_OFF;
  float* o     = ws + O_OFF;
  float* ypart = ws + YPART_OFF;
  unsigned short* qpart = (unsigned short*)(ws + QPART_OFF);
  unsigned short* apo   = (unsigned short*)(ws + APO_OFF);
  float* msum  = ws + MSUM_OFF;

  hipLaunchKernelGGL(k_proj,     dim3(544),  dim3(256), 0, stream, x, Pq, Pk, Pv, qpart);
  hipLaunchKernelGGL(k_reduce_q, dim3(544),  dim3(256), 0, stream, qpart, q, out);
  hipLaunchKernelGGL(k_copy,     dim3(4096), dim3(256), 0, stream, Kp, Vp, out);
  hipLaunchKernelGGL(k_attn,     dim3(512),  dim3(256), 0, stream, Kp, Vp, q, apo, msum);
  hipLaunchKernelGGL(k_combine,  dim3(1024), dim3(256), 0, stream, apo, msum, q, o);
  hipLaunchKernelGGL(k_out,      dim3(512),  dim3(256), 0, stream, o, Po, ypart);
  hipLaunchKernelGGL(k_reduce_y, dim3(512),  dim3(256), 0, stream, ypart, out);
}

// Round 13
// 124.127 us; speedup vs baseline: 1.1255x; 1.0939x over previous
//
#include <hip/hip_runtime.h>

#define B_ 32
#define M_ 4096
#define M1_ 4097
#define H_ 32
#define D_ 4096

typedef float float4_ __attribute__((ext_vector_type(4)));
typedef float f32x4 __attribute__((ext_vector_type(4)));
typedef short short8 __attribute__((ext_vector_type(8)));
typedef short short4_ __attribute__((ext_vector_type(4)));

#define KOFF 131072
#define VOFF 16912384

// ws layout (f32-word offsets)
#define Q_OFF     0u            // 34*32*128 = 139264
#define O_OFF     139264u       // 32*32*128 = 131072
#define YPART_OFF 270336u       // bf16 now: 8*131072 u16 = 524288 words
#define QPART_OFF 1318912u      // bf16: 16*139264 u16 = 1114112 words (dead after k_reduce_q)
#define APO_OFF   1318912u      // bf16: 512*32*128 u16 = 1048576 words (reuses qpart region)
#define MSUM_OFF  2433024u      // 512*32*2 = 32768 words -> total 2465792 f32 = 9.9 MB

#define WAITV(n) asm volatile("s_waitcnt vmcnt(" #n ")" ::: "memory")
#define SBAR() __builtin_amdgcn_sched_barrier(0)

__device__ __forceinline__ unsigned short f2bf(float f) {
  union { float f; unsigned u; } cv; cv.f = f;
  return (unsigned short)((cv.u + 0x7FFFu + ((cv.u >> 16) & 1u)) >> 16);
}
__device__ __forceinline__ float bf2f(unsigned short b) {
  union { unsigned u; float f; } cv; cv.u = ((unsigned)b) << 16;
  return cv.f;
}
__device__ __forceinline__ short8 pack8(const float* t) {
  short8 r;
#pragma unroll
  for (int j = 0; j < 8; ++j) r[j] = (short)f2bf(t[j]);
  return r;
}
__device__ __forceinline__ short8 load8cvt(const float* __restrict__ p) {
  float t[8];
  float4_ v0 = *(const float4_*)p;
  float4_ v1 = *(const float4_*)(p + 4);
#pragma unroll
  for (int j = 0; j < 4; ++j) { t[j] = v0[j]; t[4 + j] = v1[j]; }
  return pack8(t);
}
// nontemporal accessors for pure-streaming buffers
__device__ __forceinline__ float4_ ntld4(const float* p) {
  return __builtin_nontemporal_load((const float4_*)p);
}
__device__ __forceinline__ short8 load8cvt_nt(const float* __restrict__ p) {
  float t[8];
  float4_ v0 = ntld4(p);
  float4_ v1 = ntld4(p + 4);
#pragma unroll
  for (int j = 0; j < 4; ++j) { t[j] = v0[j]; t[4 + j] = v1[j]; }
  return pack8(t);
}
// async 16B global -> LDS (per-lane global src; wave-uniform LDS base + lane*16)
__device__ __forceinline__ void load_lds16(const float* g, float* l) {
  __builtin_amdgcn_global_load_lds(
      (const __attribute__((address_space(1))) unsigned int*)g,
      (__attribute__((address_space(3))) unsigned int*)l, 16, 0, 0);
}

// ---------------- kernel 1: projections, split-D=16 partials (256 d per chunk)
// NEW: W staged through LDS bf16 (coalesced float4 loads + register prefetch of
// the next chunk) replacing 128 scalar 512B-stride dword loads per wave.
__global__ __launch_bounds__(256, 4) void k_proj(const float* __restrict__ x,
    const float* __restrict__ Pq, const float* __restrict__ Pk,
    const float* __restrict__ Pv, unsigned short* __restrict__ qpart)
{
  __shared__ unsigned short Wl[2][32][128];   // 16 KB
  int bid = blockIdx.x;
  int hh = bid >> 4;
  int c  = bid & 15;
  const float* W = (hh < 32) ? (Pq + (size_t)hh * D_ * 128)
                             : ((hh == 32) ? Pk : Pv);
  int d0 = c * 256;
  int tid = threadIdx.x;
  int w = tid >> 6, l = tid & 63, l15 = l & 15, lg = l >> 4;
  int sdr = tid >> 5, sk4 = (tid & 31) * 4;   // staging coords (row-group, col*4)
  f32x4 acc[2][2] = {};          // [b-tile][n-tile]
  float4_ tmp[4];
#pragma unroll
  for (int i = 0; i < 4; ++i)
    tmp[i] = ntld4(W + (size_t)(d0 + i * 8 + sdr) * 128 + sk4);
  for (int ks = 0; ks < 8; ++ks) {
    int buf = ks & 1;
    // write staged regs -> LDS bf16
#pragma unroll
    for (int i = 0; i < 4; ++i) {
      short4_ s;
#pragma unroll
      for (int j = 0; j < 4; ++j) s[j] = (short)f2bf(tmp[i][j]);
      *(short4_*)&Wl[buf][i * 8 + sdr][sk4] = s;
    }
    // prefetch next chunk before the barrier (latency hides under compute)
    if (ks < 7) {
#pragma unroll
      for (int i = 0; i < 4; ++i)
        tmp[i] = ntld4(W + (size_t)(d0 + (ks + 1) * 32 + i * 8 + sdr) * 128 + sk4);
    }
    __syncthreads();
    int dk = d0 + ks * 32 + lg * 8;
    short8 af[2];
#pragma unroll
    for (int bt = 0; bt < 2; ++bt)
      af[bt] = load8cvt(x + (size_t)(bt * 16 + l15) * D_ + dk);
    short8 bf[2];
#pragma unroll
    for (int nti = 0; nti < 2; ++nti) {
      int col = (2 * w + nti) * 16 + l15;
      short8 t;
#pragma unroll
      for (int j = 0; j < 8; ++j) t[j] = (short)Wl[buf][lg * 8 + j][col];
      bf[nti] = t;
    }
#pragma unroll
    for (int bt = 0; bt < 2; ++bt)
#pragma unroll
      for (int nti = 0; nti < 2; ++nti)
        acc[bt][nti] = __builtin_amdgcn_mfma_f32_16x16x32_bf16(af[bt], bf[nti], acc[bt][nti], 0, 0, 0);
  }
#pragma unroll
  for (int bt = 0; bt < 2; ++bt)
#pragma unroll
    for (int nti = 0; nti < 2; ++nti) {
      int k = (2 * w + nti) * 16 + l15;
#pragma unroll
      for (int i = 0; i < 4; ++i) {
        int b = bt * 16 + lg * 4 + i;
        __builtin_nontemporal_store(f2bf(acc[bt][nti][i]),
            &qpart[(size_t)((c * 34 + hh) * 32 + b) * 128 + k]);
      }
    }
}

// ---------------- kernel 2: reduce bf16 projection partials; write new K/V cache row
__global__ __launch_bounds__(256) void k_reduce_q(const unsigned short* __restrict__ qpart,
    float* __restrict__ q, float* __restrict__ dout)
{
  int idx = blockIdx.x * 256 + threadIdx.x;   // 34*32*128 = 139264
  if (idx >= 34 * 32 * 128) return;
  float s = 0.f;
#pragma unroll
  for (int cc = 0; cc < 16; ++cc)
    s += bf2f(__builtin_nontemporal_load(&qpart[(size_t)cc * 139264 + idx]));
  q[idx] = s;
  int hh = idx >> 12;
  if (hh >= 32) {
    int b = (idx >> 7) & 31, k = idx & 127;
    size_t off = (hh == 32) ? (size_t)KOFF : (size_t)VOFF;
    __builtin_nontemporal_store(s, &dout[off + ((size_t)b * M1_ + M_) * 128 + k]);
  }
}

// ---------------- kernel 3: barrier-free wave-pipelined cache-copy + attention
// EXACT copy of the best-measured (126.3 us total, k_attn ~82 us) version.
#define ISSUE(T, KR, VB) do { \
  const float* Kc_ = Kb + (T) * 16 * 128; \
  const float* Vc_ = Vb + (T) * 16 * 128; \
  const float* Krow_ = Kc_ + (size_t)l15 * 128; \
  _Pragma("unroll") \
  for (int ks = 0; ks < 4; ++ks) { \
    KR[2 * ks]     = ntld4(Krow_ + ks * 32 + lg * 8); \
    KR[2 * ks + 1] = ntld4(Krow_ + ks * 32 + lg * 8 + 4); \
  } \
  _Pragma("unroll") \
  for (int i = 0; i < 8; ++i) load_lds16(Vc_ + i * 256 + l * 4, VB + i * 256); \
} while (0)

#define DO_CHUNK(T, KR, VB) do { \
  /* K_new store from frag regs (wave collectively row-complete) */ \
  float* Knrow_ = Knb + (T) * 16 * 128 + (size_t)l15 * 128; \
  _Pragma("unroll") \
  for (int ks = 0; ks < 4; ++ks) { \
    __builtin_nontemporal_store(KR[2 * ks],     (float4_*)(Knrow_ + ks * 32 + lg * 8)); \
    __builtin_nontemporal_store(KR[2 * ks + 1], (float4_*)(Knrow_ + ks * 32 + lg * 8 + 4)); \
  } \
  /* V_new store from LDS (coalesced) */ \
  float* Vnc_ = Vnb + (T) * 16 * 128; \
  _Pragma("unroll") \
  for (int i = 0; i < 8; ++i) { \
    float4_ t_ = *(const float4_*)(VB + (i * 64 + l) * 4); \
    __builtin_nontemporal_store(t_, (float4_*)(Vnc_ + (size_t)(i * 64 + l) * 4)); \
  } \
  /* K frags in-register cvt */ \
  short8 kf_[4]; \
  _Pragma("unroll") \
  for (int ks = 0; ks < 4; ++ks) { \
    float tt_[8]; \
    _Pragma("unroll") \
    for (int j = 0; j < 4; ++j) { tt_[j] = KR[2 * ks][j]; tt_[4 + j] = KR[2 * ks + 1][j]; } \
    kf_[ks] = pack8(tt_); \
  } \
  /* QK^T: S[h][m], m = l15 */ \
  f32x4 sacc_[2] = {}; \
  _Pragma("unroll") \
  for (int ks = 0; ks < 4; ++ks) \
    _Pragma("unroll") \
    for (int ht = 0; ht < 2; ++ht) \
      sacc_[ht] = __builtin_amdgcn_mfma_f32_16x16x32_bf16(af[ht][ks], kf_[ks], sacc_[ht], 0, 0, 0); \
  /* online softmax (cross-lane within 16-lane groups) */ \
  _Pragma("unroll") \
  for (int ht = 0; ht < 2; ++ht) { \
    f32x4 mx_; \
    _Pragma("unroll") \
    for (int i = 0; i < 4; ++i) { \
      float v_ = sacc_[ht][i]; \
      v_ = fmaxf(v_, __shfl_xor(v_, 1)); v_ = fmaxf(v_, __shfl_xor(v_, 2)); \
      v_ = fmaxf(v_, __shfl_xor(v_, 4)); v_ = fmaxf(v_, __shfl_xor(v_, 8)); \
      mx_[i] = v_; \
    } \
    f32x4 fsc_; \
    _Pragma("unroll") \
    for (int i = 0; i < 4; ++i) { \
      float mn_ = fmaxf(mrun[ht][i], mx_[i]); \
      fsc_[i] = __expf(mrun[ht][i] - mn_); \
      mrun[ht][i] = mn_; \
    } \
    _Pragma("unroll") \
    for (int vt = 0; vt < 8; ++vt) oacc[ht][vt] *= fsc_; \
    _Pragma("unroll") \
    for (int i = 0; i < 4; ++i) { \
      float p_ = __expf(sacc_[ht][i] - mrun[ht][i]); \
      lsum[ht][i] = lsum[ht][i] * fsc_[i] + p_; \
      Plds[w][ht * 16 + lg * 4 + i][l15] = f2bf(p_); \
    } \
  } \
  asm volatile("" ::: "memory"); \
  /* PV: 16x16x32 with upper K-half zeroed (contraction m=16) */ \
  short8 z_ = {}; \
  short8 pa_[2]; \
  _Pragma("unroll") \
  for (int ht = 0; ht < 2; ++ht) \
    pa_[ht] = (lg < 2) ? *(const short8*)&Plds[w][ht * 16 + l15][lg * 8] : z_; \
  _Pragma("unroll") \
  for (int vt = 0; vt < 8; ++vt) { \
    short8 bfv_ = z_; \
    if (lg < 2) { \
      float t_[8]; \
      _Pragma("unroll") \
      for (int j = 0; j < 8; ++j) t_[j] = VB[(lg * 8 + j) * 128 + vt * 16 + l15]; \
      bfv_ = pack8(t_); \
    } \
    _Pragma("unroll") \
    for (int ht = 0; ht < 2; ++ht) \
      oacc[ht][vt] = __builtin_amdgcn_mfma_f32_16x16x32_bf16(pa_[ht], bfv_, oacc[ht][vt], 0, 0, 0); \
  } \
} while (0)

__global__ __launch_bounds__(256, 2) void k_attn(const float* __restrict__ Kp,
    const float* __restrict__ Vp, const float* __restrict__ q,
    float* __restrict__ dout, unsigned short* __restrict__ apo,
    float* __restrict__ msum)
{
  __shared__ float Vbuf[4][2][2048];          // per-wave V dbuf (DMA dst), 64 KB
  __shared__ unsigned short Plds[4][32][16];  // per-wave P tile, 4 KB
  __shared__ float Mh[4][32], Sh[4][32];      // per-wave softmax stats (epilogue)
  int bid = blockIdx.x;
  int b = bid >> 4;
  int tid = threadIdx.x, w = tid >> 6, l = tid & 63, l15 = l & 15, lg = l >> 4;
  int wid = (bid & 15) * 4 + w;               // 0..63 per b
  const float* Kb = Kp + ((size_t)b * M_ + wid * 64) * 128;
  const float* Vb = Vp + ((size_t)b * M_ + wid * 64) * 128;
  float* Knb = dout + KOFF + ((size_t)b * M1_ + wid * 64) * 128;
  float* Vnb = dout + VOFF + ((size_t)b * M1_ + wid * 64) * 128;
  float* vb0 = &Vbuf[w][0][0];
  float* vb1 = &Vbuf[w][1][0];

  // q fragments, once per wave (16 b128 loads; q is hot/cached)
  short8 af[2][4];
#pragma unroll
  for (int ks = 0; ks < 4; ++ks)
#pragma unroll
    for (int ht = 0; ht < 2; ++ht)
      af[ht][ks] = load8cvt(q + (size_t)((ht * 16 + l15) * 32 + b) * 128 + ks * 32 + lg * 8);

  float4_ krA[8], krB[8];
  f32x4 mrun[2], lsum[2], oacc[2][8];
#pragma unroll
  for (int ht = 0; ht < 2; ++ht) {
#pragma unroll
    for (int i = 0; i < 4; ++i) { mrun[ht][i] = -3e38f; lsum[ht][i] = 0.f; }
#pragma unroll
    for (int vt = 0; vt < 8; ++vt) oacc[ht][vt] = f32x4{0.f, 0.f, 0.f, 0.f};
  }

  // pipeline: vmem queue order is [q16][c0 16] | [c1 16][st0 16] | [c2][st1] | [c3][st2] | [st3]
  ISSUE(0, krA, vb0); SBAR();
  ISSUE(1, krB, vb1); SBAR();
  WAITV(16); SBAR();              // q + chunk0 complete
  DO_CHUNK(0, krA, vb0);
  ISSUE(2, krA, vb0); SBAR();
  WAITV(32); SBAR();              // chunk1 complete
  DO_CHUNK(1, krB, vb1);
  ISSUE(3, krB, vb1); SBAR();
  WAITV(32); SBAR();              // chunk2 complete
  DO_CHUNK(2, krA, vb0);
  WAITV(16); SBAR();              // chunk3 complete
  DO_CHUNK(3, krB, vb1);

  // ---- epilogue: per-wave sum reduce, then 4-wave flash-merge in LDS ----
#pragma unroll
  for (int ht = 0; ht < 2; ++ht)
#pragma unroll
    for (int i = 0; i < 4; ++i) {
      float s = lsum[ht][i];
      s += __shfl_xor(s, 1); s += __shfl_xor(s, 2);
      s += __shfl_xor(s, 4); s += __shfl_xor(s, 8);
      lsum[ht][i] = s;
    }
  if (l15 == 0) {
#pragma unroll
    for (int ht = 0; ht < 2; ++ht)
#pragma unroll
      for (int i = 0; i < 4; ++i) {
        int h = ht * 16 + lg * 4 + i;
        Mh[w][h] = mrun[ht][i];
        Sh[w][h] = lsum[ht][i];
      }
  }
  __syncthreads();
  // scale own O by exp(m_w - m*) into this wave's (now dead) Vbuf region
  float* Ob = &Vbuf[w][0][0];
#pragma unroll
  for (int ht = 0; ht < 2; ++ht)
#pragma unroll
    for (int i = 0; i < 4; ++i) {
      int h = ht * 16 + lg * 4 + i;
      float ms = fmaxf(fmaxf(Mh[0][h], Mh[1][h]), fmaxf(Mh[2][h], Mh[3][h]));
      float f = __expf(mrun[ht][i] - ms);
#pragma unroll
      for (int vt = 0; vt < 8; ++vt)
        Ob[h * 128 + vt * 16 + l15] = oacc[ht][vt][i] * f;
    }
  __syncthreads();
  int blk = bid & 15;
  size_t sblk = ((size_t)b * 16 + blk) * 32;
  if (tid < 32) {
    int h = tid;
    float ms = fmaxf(fmaxf(Mh[0][h], Mh[1][h]), fmaxf(Mh[2][h], Mh[3][h]));
    float ss = Sh[0][h] * __expf(Mh[0][h] - ms) + Sh[1][h] * __expf(Mh[1][h] - ms)
             + Sh[2][h] * __expf(Mh[2][h] - ms) + Sh[3][h] * __expf(Mh[3][h] - ms);
    msum[(sblk + h) * 2]     = ms;
    msum[(sblk + h) * 2 + 1] = ss;
  }
  const float* Vall = &Vbuf[0][0][0];
  for (int idx = tid; idx < 4096; idx += 256) {
    float s = Vall[idx] + Vall[4096 + idx] + Vall[8192 + idx] + Vall[12288 + idx];
    __builtin_nontemporal_store(f2bf(s), &apo[(sblk + (idx >> 7)) * 128 + (idx & 127)]);
  }
}

// ---------------- kernel 4: combine 16 block partials + exact extra-token -> o
__global__ __launch_bounds__(256) void k_combine(const unsigned short* __restrict__ apo,
    const float* __restrict__ msum, const float* __restrict__ q, float* __restrict__ o)
{
  __shared__ float redN[4][128];
  __shared__ float redD[4];
  int bid = blockIdx.x;            // 1024: b*32+h
  int b = bid >> 5, h = bid & 31;
  int tid = threadIdx.x, w = tid >> 6, l = tid & 63;

  // exact f32 extra-token logit: e = q[h] . k_new
  const float* qh = q + (size_t)(h * 32 + b) * 128;
  const float* kn = q + (size_t)(1024 + b) * 128;
  const float* vn = q + (size_t)(1056 + b) * 128;
  float e = qh[2 * l] * kn[2 * l] + qh[2 * l + 1] * kn[2 * l + 1];
#pragma unroll
  for (int d = 1; d < 64; d <<= 1) e += __shfl_xor(e, d);

  float gm = (l < 16) ? msum[((size_t)(b * 16 + l) * 32 + h) * 2] : -3e38f;
#pragma unroll
  for (int d = 1; d < 64; d <<= 1) gm = fmaxf(gm, __shfl_xor(gm, d));
  gm = fmaxf(gm, e);
  float pe = __expf(e - gm);

  float num0 = 0.f, num1 = 0.f, den = 0.f;
#pragma unroll
  for (int i = 0; i < 4; ++i) {
    int cc = w * 4 + i;
    size_t slot = (size_t)(b * 16 + cc) * 32 + h;
    float sc = __expf(msum[slot * 2] - gm);
    den += sc * msum[slot * 2 + 1];
    unsigned pp = __builtin_nontemporal_load((const unsigned*)&apo[slot * 128 + l * 2]);
    num0 += sc * bf2f((unsigned short)(pp & 0xFFFFu));
    num1 += sc * bf2f((unsigned short)(pp >> 16));
  }
  redN[w][l * 2] = num0;
  redN[w][l * 2 + 1] = num1;
  if (l == 0) redD[w] = den + (w == 0 ? pe : 0.f);
  __syncthreads();
  if (tid < 128) {
    float num = redN[0][tid] + redN[1][tid] + redN[2][tid] + redN[3][tid] + pe * vn[tid];
    float dd  = redD[0] + redD[1] + redD[2] + redD[3];
    o[((size_t)(b * 32 + h)) * 128 + tid] = num / dd;
  }
}

// ---------------- kernel 5: y partials = o x P_o  (grid 512; ypart now bf16)
__global__ __launch_bounds__(256) void k_out(const float* __restrict__ o,
    const float* __restrict__ Po, unsigned short* __restrict__ ypart)
{
  int bid = blockIdx.x;
  int dt = bid >> 3, hg = bid & 7;
  int tid = threadIdx.x, w = tid >> 6, l = tid & 63, l15 = l & 15, lg = l >> 4;
  int d = dt * 64 + w * 16 + l15;
  f32x4 acc[2] = {};               // [b-tile]
  for (int hi = 0; hi < 4; ++hi) {
    int h = hg * 4 + hi;
#pragma unroll
    for (int ks = 0; ks < 4; ++ks) {
      short8 af[2];
#pragma unroll
      for (int bt = 0; bt < 2; ++bt)
        af[bt] = load8cvt(o + ((size_t)((bt * 16 + l15) * 32 + h)) * 128 + ks * 32 + lg * 8);
      short8 bf = load8cvt_nt(Po + ((size_t)h * D_ + d) * 128 + ks * 32 + lg * 8);
#pragma unroll
      for (int bt = 0; bt < 2; ++bt)
        acc[bt] = __builtin_amdgcn_mfma_f32_16x16x32_bf16(af[bt], bf, acc[bt], 0, 0, 0);
    }
  }
#pragma unroll
  for (int bt = 0; bt < 2; ++bt)
#pragma unroll
    for (int i = 0; i < 4; ++i) {
      int b = bt * 16 + lg * 4 + i;
      __builtin_nontemporal_store(f2bf(acc[bt][i]),
          &ypart[((size_t)(hg * 32 + b)) * 4096 + d]);
    }
}

// ---------------- kernel 6: reduce bf16 y partials -> y
__global__ __launch_bounds__(256) void k_reduce_y(const unsigned short* __restrict__ ypart,
    float* __restrict__ dout)
{
  int idx = blockIdx.x * 256 + threadIdx.x;  // 131072
  float s = 0.f;
#pragma unroll
  for (int g = 0; g < 8; ++g)
    s += bf2f(__builtin_nontemporal_load(&ypart[(size_t)g * 131072 + idx]));
  dout[idx] = s;
}

extern "C" void kernel_launch(void* const* d_in, const int* in_sizes, int n_in,
                              void* d_out, int out_size, void* d_ws, size_t ws_size,
                              hipStream_t stream) {
  (void)in_sizes; (void)n_in; (void)out_size; (void)ws_size;
  const float* x  = (const float*)d_in[0];
  const float* Kp = (const float*)d_in[1];
  const float* Vp = (const float*)d_in[2];
  const float* Pq = (const float*)d_in[3];
  const float* Pk = (const float*)d_in[4];
  const float* Pv = (const float*)d_in[5];
  const float* Po = (const float*)d_in[6];
  float* out = (float*)d_out;
  float* ws  = (float*)d_ws;
  float* q     = ws + Q_OFF;
  float* o     = ws + O_OFF;
  unsigned short* ypart = (unsigned short*)(ws + YPART_OFF);
  unsigned short* qpart = (unsigned short*)(ws + QPART_OFF);
  unsigned short* apo   = (unsigned short*)(ws + APO_OFF);
  float* msum  = ws + MSUM_OFF;

  hipLaunchKernelGGL(k_proj,     dim3(544),  dim3(256), 0, stream, x, Pq, Pk, Pv, qpart);
  hipLaunchKernelGGL(k_reduce_q, dim3(544),  dim3(256), 0, stream, qpart, q, out);
  hipLaunchKernelGGL(k_attn,     dim3(512),  dim3(256), 0, stream, Kp, Vp, q, out, apo, msum);
  hipLaunchKernelGGL(k_combine,  dim3(1024), dim3(256), 0, stream, apo, msum, q, o);
  hipLaunchKernelGGL(k_out,      dim3(512),  dim3(256), 0, stream, o, Po, ypart);
  hipLaunchKernelGGL(k_reduce_y, dim3(512),  dim3(256), 0, stream, ypart, out);
}